// Round 4
// baseline (514.243 us; speedup 1.0000x reference)
//
#include <hip/hip_runtime.h>

// Batched ADMM QP solver, register-heavy form. One block (128 thr, 2 waves) per batch.
// Setup (all matrices register/LDS hybrid):
//   K = AtA + Q + sigma*I  computed directly into GJ register layout
//   Kinv via register-resident Gauss-Jordan (SPD, no pivoting; 16-unrolled)
//   c = Kinv*p, d = -A*c
//   P = A*Kinv*At built per-wave into pacc[5][10] registers via two C1-half passes
// Iterate 799x:  s = P*w + d + y; z = clip(s,l,u); y = s-z; w = z-y
// Epilogue: x = Kinv*(At*w) - c
// Round-4 fix: w-write row index was missing the wvi*40 wave offset (race + rows
// 40..79 never updated -> divergence).

#define ITERS 800
#define SIGMA 1e-6f
#define WAM 68          // amat row stride

__global__ __launch_bounds__(128, 2)
void admm_qp_kernel(const float* __restrict__ Q, const float* __restrict__ p,
                    const float* __restrict__ A, const float* __restrict__ bvec,
                    const float* __restrict__ G, const float* __restrict__ h,
                    float* __restrict__ out)
{
    __shared__ float amat[80 * WAM];   // [A;G], stride 68
    __shared__ float X[64 * 64];       // Kinv dump / C1-half scratch
    __shared__ float wbuf[2 * 80];
    __shared__ float fcol[64];
    __shared__ float prow[64];
    __shared__ float pvec[64];
    __shared__ float cvec[64];
    __shared__ float dvec[80];
    __shared__ float lvec[80];
    __shared__ float uvec[80];

    const int b  = blockIdx.x;
    const int t  = threadIdx.x;
    const int wvi = t >> 6;            // wave 0/1
    const int ln = t & 63;

    const float* Ab = A + (size_t)b * 16 * 64;
    const float* Gb = G + (size_t)b * 64 * 64;
    const float* Qb = Q + (size_t)b * 64 * 64;

    // ---- stage Amat, pvec, bounds, w0 ----
    for (int e = t; e < 80 * 16; e += 128) {
        int row = e >> 4, seg = e & 15;
        const float* src = (row < 16) ? (Ab + row * 64 + seg * 4)
                                      : (Gb + (row - 16) * 64 + seg * 4);
        *(float4*)&amat[row * WAM + seg * 4] = *(const float4*)src;
    }
    if (t < 64) pvec[t] = p[(size_t)b * 64 + t];
    if (t < 80) {
        float lo, up;
        if (t < 16) { lo = up = bvec[(size_t)b * 16 + t]; }
        else        { lo = -1e8f; up = h[(size_t)b * 64 + (t - 16)]; }
        lvec[t] = lo; uvec[t] = up; wbuf[t] = 0.f;
    }
    __syncthreads();

    // ---- AtA directly in GJ layout: thread (rp,qc) owns rows {2rp,2rp+1} x cols qc*16..+15
    const int rp = t >> 2;             // 0..31
    const int qc = t & 3;              // 0..3
    float ar0[16], ar1[16];
#pragma unroll
    for (int c = 0; c < 16; ++c) { ar0[c] = 0.f; ar1[c] = 0.f; }
    for (int k = 0; k < 80; ++k) {
        const float* rowk = &amat[k * WAM];
        float2 av = *(const float2*)&rowk[2 * rp];
#pragma unroll
        for (int c4 = 0; c4 < 4; ++c4) {
            float4 bv = *(const float4*)&rowk[qc * 16 + 4 * c4];
            ar0[4*c4+0] += av.x * bv.x; ar0[4*c4+1] += av.x * bv.y;
            ar0[4*c4+2] += av.x * bv.z; ar0[4*c4+3] += av.x * bv.w;
            ar1[4*c4+0] += av.y * bv.x; ar1[4*c4+1] += av.y * bv.y;
            ar1[4*c4+2] += av.y * bv.z; ar1[4*c4+3] += av.y * bv.w;
        }
    }
    {   // + Q + sigma*I
        const float* q0 = &Qb[(2 * rp) * 64 + qc * 16];
        const float* q1 = &Qb[(2 * rp + 1) * 64 + qc * 16];
#pragma unroll
        for (int c4 = 0; c4 < 4; ++c4) {
            float4 v0 = *(const float4*)&q0[4 * c4];
            float4 v1 = *(const float4*)&q1[4 * c4];
            ar0[4*c4+0] += v0.x; ar0[4*c4+1] += v0.y; ar0[4*c4+2] += v0.z; ar0[4*c4+3] += v0.w;
            ar1[4*c4+0] += v1.x; ar1[4*c4+1] += v1.y; ar1[4*c4+2] += v1.z; ar1[4*c4+3] += v1.w;
        }
#pragma unroll
        for (int c = 0; c < 16; ++c) {
            int col = qc * 16 + c;
            if (col == 2 * rp)     ar0[c] += SIGMA;
            if (col == 2 * rp + 1) ar1[c] += SIGMA;
        }
    }

    // ---- register-resident Gauss-Jordan (in-place Kinv; pivot index static via unroll) ----
    for (int po = 0; po < 4; ++po) {
#pragma unroll
        for (int pi = 0; pi < 16; ++pi) {
            const int pv = po * 16 + pi;
            if (qc == po)
                *(float2*)&fcol[2 * rp] = make_float2(ar0[pi], ar1[pi]);
            __syncthreads();
            float pr = 1.0f / fcol[pv];
            float2 ff = *(const float2*)&fcol[2 * rp];
            if (rp == (pv >> 1)) {
                float sp[16];
#pragma unroll
                for (int c = 0; c < 16; ++c)
                    sp[c] = ((pv & 1) ? ar1[c] : ar0[c]) * pr;
                if (qc == po) sp[pi] = pr;
#pragma unroll
                for (int c4 = 0; c4 < 4; ++c4)
                    *(float4*)&prow[qc * 16 + 4 * c4] =
                        make_float4(sp[4*c4], sp[4*c4+1], sp[4*c4+2], sp[4*c4+3]);
            }
            __syncthreads();
            float sp[16];
#pragma unroll
            for (int c4 = 0; c4 < 4; ++c4) {
                float4 v = *(const float4*)&prow[qc * 16 + 4 * c4];
                sp[4*c4] = v.x; sp[4*c4+1] = v.y; sp[4*c4+2] = v.z; sp[4*c4+3] = v.w;
            }
            if (rp == (pv >> 1)) {
                if ((pv & 1) == 0) {
#pragma unroll
                    for (int c = 0; c < 16; ++c) { ar1[c] -= ff.y * sp[c]; ar0[c] = sp[c]; }
                    if (qc == po) ar1[pi] = -ff.y * pr;
                } else {
#pragma unroll
                    for (int c = 0; c < 16; ++c) { ar0[c] -= ff.x * sp[c]; ar1[c] = sp[c]; }
                    if (qc == po) ar0[pi] = -ff.x * pr;
                }
            } else {
#pragma unroll
                for (int c = 0; c < 16; ++c) { ar0[c] -= ff.x * sp[c]; ar1[c] -= ff.y * sp[c]; }
                if (qc == po) { ar0[pi] = -ff.x * pr; ar1[pi] = -ff.y * pr; }
            }
        }
    }

    // ---- dump Kinv -> X ----
#pragma unroll
    for (int c4 = 0; c4 < 4; ++c4) {
        *(float4*)&X[(2*rp)*64   + qc*16 + 4*c4] = make_float4(ar0[4*c4], ar0[4*c4+1], ar0[4*c4+2], ar0[4*c4+3]);
        *(float4*)&X[(2*rp+1)*64 + qc*16 + 4*c4] = make_float4(ar1[4*c4], ar1[4*c4+1], ar1[4*c4+2], ar1[4*c4+3]);
    }
    __syncthreads();

    // ---- c = Kinv*p ----
    if (t < 64) {
        float acc = 0.f;
        for (int k4 = 0; k4 < 16; ++k4) {
            float4 kv = *(const float4*)&X[t * 64 + 4 * k4];
            float4 pv4 = *(const float4*)&pvec[4 * k4];
            acc += kv.x * pv4.x + kv.y * pv4.y + kv.z * pv4.z + kv.w * pv4.w;
        }
        cvec[t] = acc;
    }
    __syncthreads();
    // ---- d = -A*c ----
    if (t < 80) {
        float acc = 0.f;
        for (int k4 = 0; k4 < 16; ++k4) {
            float4 avv = *(const float4*)&amat[t * WAM + 4 * k4];
            float4 cv4 = *(const float4*)&cvec[4 * k4];
            acc += avv.x * cv4.x + avv.y * cv4.y + avv.z * cv4.z + avv.w * cv4.w;
        }
        dvec[t] = -acc;
    }
    __syncthreads();

    // ---- P fragments via two C1-half passes ----
    const int rg = ln >> 3;            // 0..7
    const int cc = ln & 7;             // 0..7
    float pacc[5][10];
#pragma unroll
    for (int j = 0; j < 5; ++j)
#pragma unroll
        for (int c = 0; c < 10; ++c) pacc[j][c] = 0.f;

    const int jg = t >> 4;             // 0..7
    const int kc = t & 15;             // 0..15
    for (int pass = 0; pass < 2; ++pass) {
        if (pass == 1) {
            __syncthreads();           // wave0 P-frag reads of X done
#pragma unroll
            for (int c4 = 0; c4 < 4; ++c4) {   // re-dump Kinv
                *(float4*)&X[(2*rp)*64   + qc*16 + 4*c4] = make_float4(ar0[4*c4], ar0[4*c4+1], ar0[4*c4+2], ar0[4*c4+3]);
                *(float4*)&X[(2*rp+1)*64 + qc*16 + 4*c4] = make_float4(ar1[4*c4], ar1[4*c4+1], ar1[4*c4+2], ar1[4*c4+3]);
            }
        }
        __syncthreads();
        // C1 half: rows pass*40 + jg*5 + jj, cols kc*4..+3 ; C1 = A*Kinv
        float c1r[5][4];
#pragma unroll
        for (int jj = 0; jj < 5; ++jj)
#pragma unroll
            for (int cx = 0; cx < 4; ++cx) c1r[jj][cx] = 0.f;
        const int jbase = pass * 40 + jg * 5;
        for (int ib = 0; ib < 16; ++ib) {
            float4 kv0 = *(const float4*)&X[(4*ib+0)*64 + kc*4];
            float4 kv1 = *(const float4*)&X[(4*ib+1)*64 + kc*4];
            float4 kv2 = *(const float4*)&X[(4*ib+2)*64 + kc*4];
            float4 kv3 = *(const float4*)&X[(4*ib+3)*64 + kc*4];
#pragma unroll
            for (int jj = 0; jj < 5; ++jj) {
                float4 aj = *(const float4*)&amat[(jbase + jj) * WAM + 4 * ib];
                c1r[jj][0] += aj.x*kv0.x + aj.y*kv1.x + aj.z*kv2.x + aj.w*kv3.x;
                c1r[jj][1] += aj.x*kv0.y + aj.y*kv1.y + aj.z*kv2.y + aj.w*kv3.y;
                c1r[jj][2] += aj.x*kv0.z + aj.y*kv1.z + aj.z*kv2.z + aj.w*kv3.z;
                c1r[jj][3] += aj.x*kv0.w + aj.y*kv1.w + aj.z*kv2.w + aj.w*kv3.w;
            }
        }
        __syncthreads();               // all Kinv reads done before overwrite
#pragma unroll
        for (int jj = 0; jj < 5; ++jj)
            *(float4*)&X[(jg*5+jj)*64 + kc*4] =
                make_float4(c1r[jj][0], c1r[jj][1], c1r[jj][2], c1r[jj][3]);
        __syncthreads();
        // P fragment for the owning wave: pacc[jj][c] = sum_k C1[row][k]*A[col][k]
        if (wvi == pass) {
            for (int kb = 0; kb < 16; ++kb) {
                float4 cv0 = *(const float4*)&X[(rg*5+0)*64 + kb*4];
                float4 cv1 = *(const float4*)&X[(rg*5+1)*64 + kb*4];
                float4 cv2 = *(const float4*)&X[(rg*5+2)*64 + kb*4];
                float4 cv3 = *(const float4*)&X[(rg*5+3)*64 + kb*4];
                float4 cv4 = *(const float4*)&X[(rg*5+4)*64 + kb*4];
#pragma unroll
                for (int c = 0; c < 10; ++c) {
                    float4 av = *(const float4*)&amat[(cc*10+c)*WAM + 4*kb];
                    pacc[0][c] += cv0.x*av.x + cv0.y*av.y + cv0.z*av.z + cv0.w*av.w;
                    pacc[1][c] += cv1.x*av.x + cv1.y*av.y + cv1.z*av.z + cv1.w*av.w;
                    pacc[2][c] += cv2.x*av.x + cv2.y*av.y + cv2.z*av.z + cv2.w*av.w;
                    pacc[3][c] += cv3.x*av.x + cv3.y*av.y + cv3.z*av.z + cv3.w*av.w;
                    pacc[4][c] += cv4.x*av.x + cv4.y*av.y + cv4.z*av.z + cv4.w*av.w;
                }
            }
        }
    }
    __syncthreads();

    // ---- per-lane row state (rows wvi*40 + rg*5 + j) ----
    const int rows0 = wvi * 40 + rg * 5;
    float dR[5], lR[5], uR[5], dyR[5];
#pragma unroll
    for (int j = 0; j < 5; ++j) {
        dR[j] = dvec[rows0 + j]; lR[j] = lvec[rows0 + j]; uR[j] = uvec[rows0 + j];
        dyR[j] = dR[j];           // y0 = 0 -> dy = d
    }
    __syncthreads();

    // ---- 799 iterations: s = P*w + d + y; z = clip; y = s-z; w = z-y ----
#define ACCF(vv, c2) \
    a0 += pacc[0][2*c2]*vv.x + pacc[0][2*c2+1]*vv.y; \
    a1 += pacc[1][2*c2]*vv.x + pacc[1][2*c2+1]*vv.y; \
    a2 += pacc[2][2*c2]*vv.x + pacc[2][2*c2+1]*vv.y; \
    a3 += pacc[3][2*c2]*vv.x + pacc[3][2*c2+1]*vv.y; \
    a4 += pacc[4][2*c2]*vv.x + pacc[4][2*c2+1]*vv.y;
#define UPD(j, aj, wj) \
    { float s = aj + dyR[j]; float z = fminf(fmaxf(s, lR[j]), uR[j]); \
      float yn = s - z; dyR[j] = dR[j] + yn; wj = z - yn; }

    for (int it = 0; it < ITERS - 1; ++it) {
        const float* wc = &wbuf[(it & 1) * 80 + cc * 10];
        float* wn = &wbuf[((it + 1) & 1) * 80];
        float2 v0 = *(const float2*)&wc[0];
        float2 v1 = *(const float2*)&wc[2];
        float2 v2 = *(const float2*)&wc[4];
        float2 v3 = *(const float2*)&wc[6];
        float2 v4 = *(const float2*)&wc[8];
        float a0 = 0.f, a1 = 0.f, a2 = 0.f, a3 = 0.f, a4 = 0.f;
        ACCF(v0, 0) ACCF(v1, 1) ACCF(v2, 2) ACCF(v3, 3) ACCF(v4, 4)
        a0 += __shfl_xor(a0, 1, 64); a0 += __shfl_xor(a0, 2, 64); a0 += __shfl_xor(a0, 4, 64);
        a1 += __shfl_xor(a1, 1, 64); a1 += __shfl_xor(a1, 2, 64); a1 += __shfl_xor(a1, 4, 64);
        a2 += __shfl_xor(a2, 1, 64); a2 += __shfl_xor(a2, 2, 64); a2 += __shfl_xor(a2, 4, 64);
        a3 += __shfl_xor(a3, 1, 64); a3 += __shfl_xor(a3, 2, 64); a3 += __shfl_xor(a3, 4, 64);
        a4 += __shfl_xor(a4, 1, 64); a4 += __shfl_xor(a4, 2, 64); a4 += __shfl_xor(a4, 4, 64);
        float w0, w1, w2, w3, w4;
        UPD(0, a0, w0) UPD(1, a1, w1) UPD(2, a2, w2) UPD(3, a3, w3) UPD(4, a4, w4)
        float wsel = w0;
        wsel = (cc == 1) ? w1 : wsel;
        wsel = (cc == 2) ? w2 : wsel;
        wsel = (cc == 3) ? w3 : wsel;
        wsel = (cc == 4) ? w4 : wsel;
        if (cc < 5) wn[wvi * 40 + rg * 5 + cc] = wsel;   // FIX: include wave offset
        __syncthreads();
    }

    // ---- epilogue: x = Kinv*(At*w) - c ----
    const float* wf = &wbuf[80];       // w_799 (799 iterations -> buffer 1)
    if (t < 64) {
        float acc = 0.f;
        for (int j = 0; j < 80; ++j) acc += amat[j * WAM + t] * wf[j];
        fcol[t] = acc;
    }
    __syncthreads();
    float xp0 = 0.f, xp1 = 0.f;
#pragma unroll
    for (int c4 = 0; c4 < 4; ++c4) {
        float4 fv = *(const float4*)&fcol[qc * 16 + 4 * c4];
        xp0 += ar0[4*c4]*fv.x + ar0[4*c4+1]*fv.y + ar0[4*c4+2]*fv.z + ar0[4*c4+3]*fv.w;
        xp1 += ar1[4*c4]*fv.x + ar1[4*c4+1]*fv.y + ar1[4*c4+2]*fv.z + ar1[4*c4+3]*fv.w;
    }
    xp0 += __shfl_xor(xp0, 1, 64); xp0 += __shfl_xor(xp0, 2, 64);
    xp1 += __shfl_xor(xp1, 1, 64); xp1 += __shfl_xor(xp1, 2, 64);
    if (qc == 0) {
        out[(size_t)b * 64 + 2 * rp]     = xp0 - cvec[2 * rp];
        out[(size_t)b * 64 + 2 * rp + 1] = xp1 - cvec[2 * rp + 1];
    }
}

extern "C" void kernel_launch(void* const* d_in, const int* in_sizes, int n_in,
                              void* d_out, int out_size, void* d_ws, size_t ws_size,
                              hipStream_t stream) {
    const float* Q    = (const float*)d_in[0];
    const float* p    = (const float*)d_in[1];
    const float* A    = (const float*)d_in[2];
    const float* bvec = (const float*)d_in[3];
    const float* G    = (const float*)d_in[4];
    const float* h    = (const float*)d_in[5];
    float* out = (float*)d_out;
    admm_qp_kernel<<<1024, 128, 0, stream>>>(Q, p, A, bvec, G, h, out);
}

// Round 5
// 426.881 us; speedup vs baseline: 1.2047x; 1.2047x over previous
//
#include <hip/hip_runtime.h>

// Batched ADMM QP solver, register-heavy form. One block (128 thr, 2 waves) per batch.
// Setup: K = AtA + Q + sigma*I in GJ register layout; Kinv via register GJ;
//   c = Kinv*p, d = -A*c; P = A*Kinv*At per-lane frags pacc[5][10].
// Iterate 799x:  s = P*w + d + y; z = clip(s,l,u); y = s-z; w = z-y
// Epilogue: x = Kinv*(At*w) - c
// Round-5: cross-lane reductions via DPP (VALU pipe) instead of __shfl_xor
// (ds_swizzle, DS pipe); w buffer repacked to 12-float-padded rows so the
// per-lane 10-float read is b128+b128+b64 (3 DS insts instead of 5).

#define ITERS 800
#define SIGMA 1e-6f
#define WAM 68          // amat row stride
#define WROW 12         // padded w-row stride (10 used + 2 pad)

// x + dpp_perm(x): ctrl 0xB1 = quad_perm[1,0,3,2] (xor1), 0x4E = quad_perm[2,3,0,1]
// (xor2), 0x141 = row_half_mirror (xor7 within 8 -> completes 8-lane sum after
// the two quad steps). All VALU-pipe, no DS.
__device__ __forceinline__ float dpp_add(float x, const int ctrl) {
    int yi;
    switch (ctrl) {
        case 0xB1:  yi = __builtin_amdgcn_update_dpp(0, __float_as_int(x), 0xB1,  0xF, 0xF, true); break;
        case 0x4E:  yi = __builtin_amdgcn_update_dpp(0, __float_as_int(x), 0x4E,  0xF, 0xF, true); break;
        default:    yi = __builtin_amdgcn_update_dpp(0, __float_as_int(x), 0x141, 0xF, 0xF, true); break;
    }
    return x + __int_as_float(yi);
}

__global__ __launch_bounds__(128, 2)
void admm_qp_kernel(const float* __restrict__ Q, const float* __restrict__ p,
                    const float* __restrict__ A, const float* __restrict__ bvec,
                    const float* __restrict__ G, const float* __restrict__ h,
                    float* __restrict__ out)
{
    __shared__ float amat[80 * WAM];   // [A;G], stride 68
    __shared__ float X[64 * 64];       // Kinv dump / C1-half scratch
    __shared__ __align__(16) float wbuf[2 * 8 * WROW];  // padded w, double-buffered
    __shared__ float fcol[64];
    __shared__ float prow[64];
    __shared__ float pvec[64];
    __shared__ float cvec[64];
    __shared__ float dvec[80];
    __shared__ float lvec[80];
    __shared__ float uvec[80];

    const int b  = blockIdx.x;
    const int t  = threadIdx.x;
    const int wvi = t >> 6;            // wave 0/1
    const int ln = t & 63;

    const float* Ab = A + (size_t)b * 16 * 64;
    const float* Gb = G + (size_t)b * 64 * 64;
    const float* Qb = Q + (size_t)b * 64 * 64;

    // ---- stage Amat, pvec, bounds, w0 ----
    for (int e = t; e < 80 * 16; e += 128) {
        int row = e >> 4, seg = e & 15;
        const float* src = (row < 16) ? (Ab + row * 64 + seg * 4)
                                      : (Gb + (row - 16) * 64 + seg * 4);
        *(float4*)&amat[row * WAM + seg * 4] = *(const float4*)src;
    }
    if (t < 64) pvec[t] = p[(size_t)b * 64 + t];
    if (t < 80) {
        float lo, up;
        if (t < 16) { lo = up = bvec[(size_t)b * 16 + t]; }
        else        { lo = -1e8f; up = h[(size_t)b * 64 + (t - 16)]; }
        lvec[t] = lo; uvec[t] = up;
    }
    if (t < 8 * WROW) { wbuf[t] = 0.f; wbuf[8 * WROW + t] = 0.f; }
    __syncthreads();

    // ---- AtA directly in GJ layout: thread (rp,qc) owns rows {2rp,2rp+1} x cols qc*16..+15
    const int rp = t >> 2;             // 0..31
    const int qc = t & 3;              // 0..3
    float ar0[16], ar1[16];
#pragma unroll
    for (int c = 0; c < 16; ++c) { ar0[c] = 0.f; ar1[c] = 0.f; }
    for (int k = 0; k < 80; ++k) {
        const float* rowk = &amat[k * WAM];
        float2 av = *(const float2*)&rowk[2 * rp];
#pragma unroll
        for (int c4 = 0; c4 < 4; ++c4) {
            float4 bv = *(const float4*)&rowk[qc * 16 + 4 * c4];
            ar0[4*c4+0] += av.x * bv.x; ar0[4*c4+1] += av.x * bv.y;
            ar0[4*c4+2] += av.x * bv.z; ar0[4*c4+3] += av.x * bv.w;
            ar1[4*c4+0] += av.y * bv.x; ar1[4*c4+1] += av.y * bv.y;
            ar1[4*c4+2] += av.y * bv.z; ar1[4*c4+3] += av.y * bv.w;
        }
    }
    {   // + Q + sigma*I
        const float* q0 = &Qb[(2 * rp) * 64 + qc * 16];
        const float* q1 = &Qb[(2 * rp + 1) * 64 + qc * 16];
#pragma unroll
        for (int c4 = 0; c4 < 4; ++c4) {
            float4 v0 = *(const float4*)&q0[4 * c4];
            float4 v1 = *(const float4*)&q1[4 * c4];
            ar0[4*c4+0] += v0.x; ar0[4*c4+1] += v0.y; ar0[4*c4+2] += v0.z; ar0[4*c4+3] += v0.w;
            ar1[4*c4+0] += v1.x; ar1[4*c4+1] += v1.y; ar1[4*c4+2] += v1.z; ar1[4*c4+3] += v1.w;
        }
#pragma unroll
        for (int c = 0; c < 16; ++c) {
            int col = qc * 16 + c;
            if (col == 2 * rp)     ar0[c] += SIGMA;
            if (col == 2 * rp + 1) ar1[c] += SIGMA;
        }
    }

    // ---- register-resident Gauss-Jordan (in-place Kinv; pivot index static via unroll) ----
    for (int po = 0; po < 4; ++po) {
#pragma unroll
        for (int pi = 0; pi < 16; ++pi) {
            const int pv = po * 16 + pi;
            if (qc == po)
                *(float2*)&fcol[2 * rp] = make_float2(ar0[pi], ar1[pi]);
            __syncthreads();
            float pr = 1.0f / fcol[pv];
            float2 ff = *(const float2*)&fcol[2 * rp];
            if (rp == (pv >> 1)) {
                float sp[16];
#pragma unroll
                for (int c = 0; c < 16; ++c)
                    sp[c] = ((pv & 1) ? ar1[c] : ar0[c]) * pr;
                if (qc == po) sp[pi] = pr;
#pragma unroll
                for (int c4 = 0; c4 < 4; ++c4)
                    *(float4*)&prow[qc * 16 + 4 * c4] =
                        make_float4(sp[4*c4], sp[4*c4+1], sp[4*c4+2], sp[4*c4+3]);
            }
            __syncthreads();
            float sp[16];
#pragma unroll
            for (int c4 = 0; c4 < 4; ++c4) {
                float4 v = *(const float4*)&prow[qc * 16 + 4 * c4];
                sp[4*c4] = v.x; sp[4*c4+1] = v.y; sp[4*c4+2] = v.z; sp[4*c4+3] = v.w;
            }
            if (rp == (pv >> 1)) {
                if ((pv & 1) == 0) {
#pragma unroll
                    for (int c = 0; c < 16; ++c) { ar1[c] -= ff.y * sp[c]; ar0[c] = sp[c]; }
                    if (qc == po) ar1[pi] = -ff.y * pr;
                } else {
#pragma unroll
                    for (int c = 0; c < 16; ++c) { ar0[c] -= ff.x * sp[c]; ar1[c] = sp[c]; }
                    if (qc == po) ar0[pi] = -ff.x * pr;
                }
            } else {
#pragma unroll
                for (int c = 0; c < 16; ++c) { ar0[c] -= ff.x * sp[c]; ar1[c] -= ff.y * sp[c]; }
                if (qc == po) { ar0[pi] = -ff.x * pr; ar1[pi] = -ff.y * pr; }
            }
        }
    }

    // ---- dump Kinv -> X ----
#pragma unroll
    for (int c4 = 0; c4 < 4; ++c4) {
        *(float4*)&X[(2*rp)*64   + qc*16 + 4*c4] = make_float4(ar0[4*c4], ar0[4*c4+1], ar0[4*c4+2], ar0[4*c4+3]);
        *(float4*)&X[(2*rp+1)*64 + qc*16 + 4*c4] = make_float4(ar1[4*c4], ar1[4*c4+1], ar1[4*c4+2], ar1[4*c4+3]);
    }
    __syncthreads();

    // ---- c = Kinv*p ----
    if (t < 64) {
        float acc = 0.f;
        for (int k4 = 0; k4 < 16; ++k4) {
            float4 kv = *(const float4*)&X[t * 64 + 4 * k4];
            float4 pv4 = *(const float4*)&pvec[4 * k4];
            acc += kv.x * pv4.x + kv.y * pv4.y + kv.z * pv4.z + kv.w * pv4.w;
        }
        cvec[t] = acc;
    }
    __syncthreads();
    // ---- d = -A*c ----
    if (t < 80) {
        float acc = 0.f;
        for (int k4 = 0; k4 < 16; ++k4) {
            float4 avv = *(const float4*)&amat[t * WAM + 4 * k4];
            float4 cv4 = *(const float4*)&cvec[4 * k4];
            acc += avv.x * cv4.x + avv.y * cv4.y + avv.z * cv4.z + avv.w * cv4.w;
        }
        dvec[t] = -acc;
    }
    __syncthreads();

    // ---- P fragments via two C1-half passes ----
    const int rg = ln >> 3;            // 0..7
    const int cc = ln & 7;             // 0..7
    float pacc[5][10];
#pragma unroll
    for (int j = 0; j < 5; ++j)
#pragma unroll
        for (int c = 0; c < 10; ++c) pacc[j][c] = 0.f;

    const int jg = t >> 4;             // 0..7
    const int kc = t & 15;             // 0..15
    for (int pass = 0; pass < 2; ++pass) {
        if (pass == 1) {
            __syncthreads();           // wave0 P-frag reads of X done
#pragma unroll
            for (int c4 = 0; c4 < 4; ++c4) {   // re-dump Kinv
                *(float4*)&X[(2*rp)*64   + qc*16 + 4*c4] = make_float4(ar0[4*c4], ar0[4*c4+1], ar0[4*c4+2], ar0[4*c4+3]);
                *(float4*)&X[(2*rp+1)*64 + qc*16 + 4*c4] = make_float4(ar1[4*c4], ar1[4*c4+1], ar1[4*c4+2], ar1[4*c4+3]);
            }
        }
        __syncthreads();
        // C1 half: rows pass*40 + jg*5 + jj, cols kc*4..+3 ; C1 = A*Kinv
        float c1r[5][4];
#pragma unroll
        for (int jj = 0; jj < 5; ++jj)
#pragma unroll
            for (int cx = 0; cx < 4; ++cx) c1r[jj][cx] = 0.f;
        const int jbase = pass * 40 + jg * 5;
        for (int ib = 0; ib < 16; ++ib) {
            float4 kv0 = *(const float4*)&X[(4*ib+0)*64 + kc*4];
            float4 kv1 = *(const float4*)&X[(4*ib+1)*64 + kc*4];
            float4 kv2 = *(const float4*)&X[(4*ib+2)*64 + kc*4];
            float4 kv3 = *(const float4*)&X[(4*ib+3)*64 + kc*4];
#pragma unroll
            for (int jj = 0; jj < 5; ++jj) {
                float4 aj = *(const float4*)&amat[(jbase + jj) * WAM + 4 * ib];
                c1r[jj][0] += aj.x*kv0.x + aj.y*kv1.x + aj.z*kv2.x + aj.w*kv3.x;
                c1r[jj][1] += aj.x*kv0.y + aj.y*kv1.y + aj.z*kv2.y + aj.w*kv3.y;
                c1r[jj][2] += aj.x*kv0.z + aj.y*kv1.z + aj.z*kv2.z + aj.w*kv3.z;
                c1r[jj][3] += aj.x*kv0.w + aj.y*kv1.w + aj.z*kv2.w + aj.w*kv3.w;
            }
        }
        __syncthreads();               // all Kinv reads done before overwrite
#pragma unroll
        for (int jj = 0; jj < 5; ++jj)
            *(float4*)&X[(jg*5+jj)*64 + kc*4] =
                make_float4(c1r[jj][0], c1r[jj][1], c1r[jj][2], c1r[jj][3]);
        __syncthreads();
        // P fragment for the owning wave: pacc[jj][c] = sum_k C1[row][k]*A[col][k]
        if (wvi == pass) {
            for (int kb = 0; kb < 16; ++kb) {
                float4 cv0 = *(const float4*)&X[(rg*5+0)*64 + kb*4];
                float4 cv1 = *(const float4*)&X[(rg*5+1)*64 + kb*4];
                float4 cv2 = *(const float4*)&X[(rg*5+2)*64 + kb*4];
                float4 cv3 = *(const float4*)&X[(rg*5+3)*64 + kb*4];
                float4 cv4 = *(const float4*)&X[(rg*5+4)*64 + kb*4];
#pragma unroll
                for (int c = 0; c < 10; ++c) {
                    float4 av = *(const float4*)&amat[(cc*10+c)*WAM + 4*kb];
                    pacc[0][c] += cv0.x*av.x + cv0.y*av.y + cv0.z*av.z + cv0.w*av.w;
                    pacc[1][c] += cv1.x*av.x + cv1.y*av.y + cv1.z*av.z + cv1.w*av.w;
                    pacc[2][c] += cv2.x*av.x + cv2.y*av.y + cv2.z*av.z + cv2.w*av.w;
                    pacc[3][c] += cv3.x*av.x + cv3.y*av.y + cv3.z*av.z + cv3.w*av.w;
                    pacc[4][c] += cv4.x*av.x + cv4.y*av.y + cv4.z*av.z + cv4.w*av.w;
                }
            }
        }
    }
    __syncthreads();

    // ---- per-lane row state (rows wvi*40 + rg*5 + j) ----
    const int rows0 = wvi * 40 + rg * 5;
    float dR[5], lR[5], uR[5], dyR[5];
#pragma unroll
    for (int j = 0; j < 5; ++j) {
        dR[j] = dvec[rows0 + j]; lR[j] = lvec[rows0 + j]; uR[j] = uvec[rows0 + j];
        dyR[j] = dR[j];           // y0 = 0 -> dy = d
    }
    // padded write index for this lane's w element (row = rows0 + cc, cc<5)
    const int jrow = rows0 + cc;
    const int widx = (jrow / 10) * WROW + (jrow % 10);
    __syncthreads();

    // ---- 799 iterations: s = P*w + d + y; z = clip; y = s-z; w = z-y ----
#define ACCF4(vv, c0) \
    a0 += pacc[0][c0]*vv.x + pacc[0][c0+1]*vv.y + pacc[0][c0+2]*vv.z + pacc[0][c0+3]*vv.w; \
    a1 += pacc[1][c0]*vv.x + pacc[1][c0+1]*vv.y + pacc[1][c0+2]*vv.z + pacc[1][c0+3]*vv.w; \
    a2 += pacc[2][c0]*vv.x + pacc[2][c0+1]*vv.y + pacc[2][c0+2]*vv.z + pacc[2][c0+3]*vv.w; \
    a3 += pacc[3][c0]*vv.x + pacc[3][c0+1]*vv.y + pacc[3][c0+2]*vv.z + pacc[3][c0+3]*vv.w; \
    a4 += pacc[4][c0]*vv.x + pacc[4][c0+1]*vv.y + pacc[4][c0+2]*vv.z + pacc[4][c0+3]*vv.w;
#define ACCF2(vv, c0) \
    a0 += pacc[0][c0]*vv.x + pacc[0][c0+1]*vv.y; \
    a1 += pacc[1][c0]*vv.x + pacc[1][c0+1]*vv.y; \
    a2 += pacc[2][c0]*vv.x + pacc[2][c0+1]*vv.y; \
    a3 += pacc[3][c0]*vv.x + pacc[3][c0+1]*vv.y; \
    a4 += pacc[4][c0]*vv.x + pacc[4][c0+1]*vv.y;
#define UPD(j, aj, wj) \
    { float s = aj + dyR[j]; float z = fminf(fmaxf(s, lR[j]), uR[j]); \
      float yn = s - z; dyR[j] = dR[j] + yn; wj = z - yn; }
#define RED8(a) a = dpp_add(a, 0xB1); a = dpp_add(a, 0x4E); a = dpp_add(a, 0x141);

    for (int it = 0; it < ITERS - 1; ++it) {
        const float* wc = &wbuf[(it & 1) * 8 * WROW + cc * WROW];
        float* wn = &wbuf[((it + 1) & 1) * 8 * WROW];
        float4 v04 = *(const float4*)&wc[0];
        float4 v47 = *(const float4*)&wc[4];
        float2 v89 = *(const float2*)&wc[8];
        float a0 = 0.f, a1 = 0.f, a2 = 0.f, a3 = 0.f, a4 = 0.f;
        ACCF4(v04, 0) ACCF4(v47, 4) ACCF2(v89, 8)
        RED8(a0) RED8(a1) RED8(a2) RED8(a3) RED8(a4)
        float w0, w1, w2, w3, w4;
        UPD(0, a0, w0) UPD(1, a1, w1) UPD(2, a2, w2) UPD(3, a3, w3) UPD(4, a4, w4)
        float wsel = w0;
        wsel = (cc == 1) ? w1 : wsel;
        wsel = (cc == 2) ? w2 : wsel;
        wsel = (cc == 3) ? w3 : wsel;
        wsel = (cc == 4) ? w4 : wsel;
        if (cc < 5) wn[widx] = wsel;
        __syncthreads();
    }

    // ---- epilogue: x = Kinv*(At*w) - c ----
    const float* wf = &wbuf[8 * WROW];   // w_799 (799 iterations -> buffer 1), padded layout
    if (t < 64) {
        float acc = 0.f;
        for (int jo = 0; jo < 8; ++jo) {
#pragma unroll
            for (int ji = 0; ji < 10; ++ji)
                acc += amat[(jo * 10 + ji) * WAM + t] * wf[jo * WROW + ji];
        }
        fcol[t] = acc;
    }
    __syncthreads();
    float xp0 = 0.f, xp1 = 0.f;
#pragma unroll
    for (int c4 = 0; c4 < 4; ++c4) {
        float4 fv = *(const float4*)&fcol[qc * 16 + 4 * c4];
        xp0 += ar0[4*c4]*fv.x + ar0[4*c4+1]*fv.y + ar0[4*c4+2]*fv.z + ar0[4*c4+3]*fv.w;
        xp1 += ar1[4*c4]*fv.x + ar1[4*c4+1]*fv.y + ar1[4*c4+2]*fv.z + ar1[4*c4+3]*fv.w;
    }
    xp0 = dpp_add(xp0, 0xB1); xp0 = dpp_add(xp0, 0x4E);
    xp1 = dpp_add(xp1, 0xB1); xp1 = dpp_add(xp1, 0x4E);
    if (qc == 0) {
        out[(size_t)b * 64 + 2 * rp]     = xp0 - cvec[2 * rp];
        out[(size_t)b * 64 + 2 * rp + 1] = xp1 - cvec[2 * rp + 1];
    }
}

extern "C" void kernel_launch(void* const* d_in, const int* in_sizes, int n_in,
                              void* d_out, int out_size, void* d_ws, size_t ws_size,
                              hipStream_t stream) {
    const float* Q    = (const float*)d_in[0];
    const float* p    = (const float*)d_in[1];
    const float* A    = (const float*)d_in[2];
    const float* bvec = (const float*)d_in[3];
    const float* G    = (const float*)d_in[4];
    const float* h    = (const float*)d_in[5];
    float* out = (float*)d_out;
    admm_qp_kernel<<<1024, 128, 0, stream>>>(Q, p, A, bvec, G, h, out);
}